// Round 1
// baseline (41.419 us; speedup 1.0000x reference)
//
#include <hip/hip_runtime.h>
#include <hip/hip_bf16.h>

// out[a,b] = sum_i max_j <pano_n[a,i,:], sat_n[b,j,:]>
// sat:  [256, 64, 128] fp32  (d_in[0])  -> N = 16384 rows
// pano: [ 64, 64, 128] fp32  (d_in[1])  -> M =  4096 rows
// out:  [64, 256] fp32

typedef __bf16 bf16x8 __attribute__((ext_vector_type(8)));
typedef float  f32x4  __attribute__((ext_vector_type(4)));

__device__ __forceinline__ unsigned short f2bf_rne(float x) {
    unsigned int u = __builtin_bit_cast(unsigned int, x);
    unsigned int r = (u + 0x7FFFu + ((u >> 16) & 1u)) >> 16;
    return (unsigned short)r;
}

// One row of 128 floats per 32 lanes: L2-normalize, emit bf16.
__global__ __launch_bounds__(256) void normalize_rows(
        const float* __restrict__ in, unsigned short* __restrict__ out, int nrows) {
    int row  = blockIdx.x * 8 + (threadIdx.x >> 5);
    int lane = threadIdx.x & 31;
    if (row >= nrows) return;
    const float4 v = *reinterpret_cast<const float4*>(in + (size_t)row * 128 + lane * 4);
    float ss = v.x * v.x + v.y * v.y + v.z * v.z + v.w * v.w;
    #pragma unroll
    for (int m = 16; m >= 1; m >>= 1) ss += __shfl_xor(ss, m);
    float scale = 1.0f / fmaxf(sqrtf(ss), 1e-12f);
    ushort4 o;
    o.x = f2bf_rne(v.x * scale);
    o.y = f2bf_rne(v.y * scale);
    o.z = f2bf_rne(v.z * scale);
    o.w = f2bf_rne(v.w * scale);
    *reinterpret_cast<ushort4*>(out + (size_t)row * 128 + lane * 4) = o;
}

#define LDS_STRIDE 136  // bf16 elems per LDS row: 128 + 8 pad (272 B, 16B-aligned)

// Block tile: 256 M-rows (4 complete a's) x 256 N-cols (4 complete b's), K=128 one-shot.
// 8 waves (512 thr), wave tile 128x64 via mfma_f32_16x16x32_bf16, acc[8][4].
__global__ __launch_bounds__(512, 2) void maxsim_kernel(
        const unsigned short* __restrict__ panoN,   // [4096][128] bf16 bits
        const unsigned short* __restrict__ satN,    // [16384][128] bf16 bits
        float* __restrict__ out) {                  // [64][256]
    __shared__ unsigned short As[256 * LDS_STRIDE];
    __shared__ unsigned short Bs[256 * LDS_STRIDE];

    const int tid = threadIdx.x;
    const int ta  = blockIdx.x >> 6;   // 0..15  M-tile
    const int tb  = blockIdx.x & 63;   // 0..63  N-tile

    // ---- stage A and B tiles: 256 rows x 256 B each, coalesced 16B chunks ----
    {
        const uint4* gA = reinterpret_cast<const uint4*>(panoN + (size_t)ta * 256 * 128);
        const uint4* gB = reinterpret_cast<const uint4*>(satN  + (size_t)tb * 256 * 128);
        char* aB = reinterpret_cast<char*>(As);
        char* bB = reinterpret_cast<char*>(Bs);
        #pragma unroll
        for (int it = 0; it < 8; ++it) {
            int c = it * 512 + tid;            // chunk id 0..4095
            int row = c >> 4, seg = c & 15;    // global row-stride = 16 chunks
            *reinterpret_cast<uint4*>(aB + row * (LDS_STRIDE * 2) + seg * 16) = gA[c];
        }
        #pragma unroll
        for (int it = 0; it < 8; ++it) {
            int c = it * 512 + tid;
            int row = c >> 4, seg = c & 15;
            *reinterpret_cast<uint4*>(bB + row * (LDS_STRIDE * 2) + seg * 16) = gB[c];
        }
    }
    __syncthreads();

    const int wid = tid >> 6;          // 0..7
    const int lane = tid & 63;
    const int wm = wid >> 2;           // 0..1  (M half: rows wm*128..)
    const int wn = wid & 3;            // 0..3  (N quarter: cols wn*64.. = b_local wn)
    const int lr = lane & 15;          // A row-in-frag / B col(j)-in-frag / C col
    const int lg = lane >> 4;          // 0..3  k-group (inputs) / row-group (C)

    f32x4 acc[8][4] = {};

    const char* aBase = reinterpret_cast<const char*>(As);
    const char* bBase = reinterpret_cast<const char*>(Bs);

    #pragma unroll
    for (int ks = 0; ks < 4; ++ks) {
        const int kbyte = ks * 64 + lg * 16;   // (ks*32 + lg*8) bf16 * 2B
        bf16x8 a[8], b[4];
        #pragma unroll
        for (int m = 0; m < 8; ++m) {
            int row = wm * 128 + m * 16 + lr;
            a[m] = *reinterpret_cast<const bf16x8*>(aBase + row * (LDS_STRIDE * 2) + kbyte);
        }
        #pragma unroll
        for (int n = 0; n < 4; ++n) {
            int row = wn * 64 + n * 16 + lr;
            b[n] = *reinterpret_cast<const bf16x8*>(bBase + row * (LDS_STRIDE * 2) + kbyte);
        }
        #pragma unroll
        for (int m = 0; m < 8; ++m)
            #pragma unroll
            for (int n = 0; n < 4; ++n)
                acc[m][n] = __builtin_amdgcn_mfma_f32_16x16x32_bf16(a[m], b[n], acc[m][n], 0, 0, 0);
    }

    // ---- epilogue: rowmax over 64 cols (full j of b_local=wn), then sum rows per a ----
    // C layout: col = lane&15 (+n*16), row = (lane>>4)*4 + q (+m*16)
    float s0 = 0.f, s1 = 0.f;   // a_local = 2*wm (rows 0..63), 2*wm+1 (rows 64..127)
    #pragma unroll
    for (int m = 0; m < 8; ++m) {
        #pragma unroll
        for (int q = 0; q < 4; ++q) {
            float rm = fmaxf(fmaxf(acc[m][0][q], acc[m][1][q]),
                             fmaxf(acc[m][2][q], acc[m][3][q]));
            rm = fmaxf(rm, __shfl_xor(rm, 1));
            rm = fmaxf(rm, __shfl_xor(rm, 2));
            rm = fmaxf(rm, __shfl_xor(rm, 4));
            rm = fmaxf(rm, __shfl_xor(rm, 8));
            if (m < 4) s0 += rm; else s1 += rm;
        }
    }
    s0 += __shfl_xor(s0, 16); s0 += __shfl_xor(s0, 32);
    s1 += __shfl_xor(s1, 16); s1 += __shfl_xor(s1, 32);

    if (lane == 0) {
        const int bg = tb * 4 + wn;
        const int ag = ta * 4 + 2 * wm;
        out[ag * 256 + bg]       = s0;
        out[(ag + 1) * 256 + bg] = s1;
    }
}

extern "C" void kernel_launch(void* const* d_in, const int* in_sizes, int n_in,
                              void* d_out, int out_size, void* d_ws, size_t ws_size,
                              hipStream_t stream) {
    const float* sat  = (const float*)d_in[0];   // [256*64, 128]
    const float* pano = (const float*)d_in[1];   // [ 64*64, 128]
    float* out = (float*)d_out;                  // [64, 256]

    unsigned short* panoN = (unsigned short*)d_ws;            // 4096*128 bf16
    unsigned short* satN  = panoN + (size_t)4096 * 128;       // 16384*128 bf16

    normalize_rows<<<512,  256, 0, stream>>>(pano, panoN, 4096);
    normalize_rows<<<2048, 256, 0, stream>>>(sat,  satN, 16384);
    maxsim_kernel<<<1024, 512, 0, stream>>>(panoN, satN, out);
}

// Round 2
// 27.782 us; speedup vs baseline: 1.4909x; 1.4909x over previous
//
#include <hip/hip_runtime.h>
#include <hip/hip_bf16.h>

// out[a,b] = sum_i max_j <pano_n[a,i,:], sat_n[b,j,:]>
// d_in[0] sat  [256,64,128] fp32 -> 16384 rows (j-dim, GEMM M / C-rows)
// d_in[1] pano [ 64,64,128] fp32 ->  4096 rows (i-dim, GEMM N / C-cols)
// out [64,256] fp32

typedef __bf16 bf16x8 __attribute__((ext_vector_type(8)));
typedef float  f32x16 __attribute__((ext_vector_type(16)));
typedef unsigned int u32;

__device__ __forceinline__ void gload16(const void* g, void* l) {
    __builtin_amdgcn_global_load_lds((const __attribute__((address_space(1))) u32*)g,
                                     (__attribute__((address_space(3))) u32*)l, 16, 0, 0);
}

__device__ __forceinline__ unsigned short f2bf_rne(float x) {
    u32 u = __builtin_bit_cast(u32, x);
    return (unsigned short)((u + 0x7FFFu + ((u >> 16) & 1u)) >> 16);
}

// 32 lanes per row of 128 floats: L2-normalize, emit bf16. Handles both tensors.
__global__ __launch_bounds__(256) void normalize_all(
        const float* __restrict__ sat, const float* __restrict__ pano,
        unsigned short* __restrict__ satN, unsigned short* __restrict__ panoN) {
    int row  = blockIdx.x * 8 + (threadIdx.x >> 5);
    int lane = threadIdx.x & 31;
    const float* src;
    unsigned short* dst;
    if (row < 16384) { src = sat  + (size_t)row * 128;           dst = satN  + (size_t)row * 128; }
    else             { src = pano + (size_t)(row - 16384) * 128; dst = panoN + (size_t)(row - 16384) * 128; }
    const float4 v = *reinterpret_cast<const float4*>(src + lane * 4);
    float ss = v.x * v.x + v.y * v.y + v.z * v.z + v.w * v.w;
    #pragma unroll
    for (int m = 16; m >= 1; m >>= 1) ss += __shfl_xor(ss, m);
    float sc = 1.0f / fmaxf(sqrtf(ss), 1e-12f);
    ushort4 o;
    o.x = f2bf_rne(v.x * sc); o.y = f2bf_rne(v.y * sc);
    o.z = f2bf_rne(v.z * sc); o.w = f2bf_rne(v.w * sc);
    *reinterpret_cast<ushort4*>(dst + lane * 4) = o;
}

// Persistent: 256 blocks. Block = (pano tile pt [256 i-rows], sat group sg [4 tiles of 256 j-rows]).
// Pano tile resident in LDS (staged once); sat tiles streamed via 2 x 32KB K-half buffers,
// staging issued one full compute phase ahead (vmcnt lands before the __syncthreads drain).
// LDS linear dest + inverse-swizzled global source (global_load_lds), XOR-swizzled reads.
// A-operand = sat (C rows = j) so max_j is within-lane over acc regs; B = pano (C cols = i).
__global__ __launch_bounds__(512, 2) void maxsim_kernel(
        const unsigned short* __restrict__ satN,
        const unsigned short* __restrict__ panoN,
        float* __restrict__ out) {
    __shared__ unsigned short Plds[256 * 128];   // 64 KB pano tile, 16-slot swizzle
    __shared__ unsigned short Slds[2][256 * 64]; // 2 x 32 KB sat K-halves, 8-slot swizzle

    const int tid  = threadIdx.x;
    const int wid  = tid >> 6;
    const int lane = tid & 63;
    const int pt   = blockIdx.x >> 4;   // 0..15 pano tile
    const int sg   = blockIdx.x & 15;   // 0..15 sat group (tiles sg*4 .. sg*4+3)

    const int wm = wid >> 2;            // 0..1  j half (128 rows)
    const int wn = wid & 3;             // 0..3  i quarter (64 cols = one a)
    const int rl = lane & 31;
    const int hi = lane >> 5;

#define STAGE_SAT(stile, kh) do {                                              \
    const char* gb_ = (const char*)satN + ((size_t)(stile) * 256) * 256 + (kh) * 128; \
    char* lb_ = (char*)&Slds[kh][0];                                           \
    _Pragma("unroll")                                                          \
    for (int i_ = 0; i_ < 4; ++i_) {                                           \
        int P_ = (wid * 4 + i_) * 1024 + lane * 16;                            \
        int r_ = P_ >> 7;                                                      \
        int s_ = ((P_ >> 4) & 7) ^ (r_ & 7);                                   \
        gload16(gb_ + (size_t)r_ * 256 + s_ * 16, lb_ + P_);                   \
    } } while (0)

#define COMPUTE(kh) do {                                                       \
    const char* sb_ = (const char*)&Slds[kh][0];                               \
    const char* pb_ = (const char*)Plds;                                       \
    _Pragma("unroll")                                                          \
    for (int ks = 0; ks < 4; ++ks) {                                           \
        bf16x8 a_[4], b_[2];                                                   \
        _Pragma("unroll")                                                      \
        for (int m = 0; m < 4; ++m) {                                          \
            int row = wm * 128 + m * 32 + rl;                                  \
            a_[m] = *(const bf16x8*)(sb_ + row * 128 + ((((ks << 1) | hi) ^ (row & 7)) << 4)); \
        }                                                                      \
        _Pragma("unroll")                                                      \
        for (int n = 0; n < 2; ++n) {                                          \
            int row = wn * 64 + n * 32 + rl;                                   \
            b_[n] = *(const bf16x8*)(pb_ + row * 256 + ((((kh) * 8 + (ks << 1) + hi) ^ (row & 15)) << 4)); \
        }                                                                      \
        _Pragma("unroll")                                                      \
        for (int m = 0; m < 4; ++m)                                            \
            _Pragma("unroll")                                                  \
            for (int n = 0; n < 2; ++n)                                        \
                acc[m][n] = __builtin_amdgcn_mfma_f32_32x32x16_bf16(a_[m], b_[n], acc[m][n], 0, 0, 0); \
    } } while (0)

    // ---- prologue: pano tile (8 x 1KB chunks/wave) + sat tile0 half0 ----
    {
        const char* pg = (const char*)(panoN + (size_t)pt * 256 * 128);
        char* pl = (char*)Plds;
        #pragma unroll
        for (int i = 0; i < 8; ++i) {
            int P   = (wid * 8 + i) * 1024 + lane * 16;
            int row = P >> 8;
            int ls  = ((P >> 4) & 15) ^ (row & 15);
            gload16(pg + row * 256 + ls * 16, pl + P);
        }
    }
    STAGE_SAT(sg * 4, 0);
    __syncthreads();

    for (int t = 0; t < 4; ++t) {
        const int st = sg * 4 + t;
        f32x16 acc[4][2] = {};

        STAGE_SAT(st, 1);                       // kh1 lands during COMPUTE(0)
        __builtin_amdgcn_sched_barrier(0);
        COMPUTE(0);
        __syncthreads();

        if (t < 3) {
            STAGE_SAT(st + 1, 0);               // next tile kh0 lands during COMPUTE(1)
            __builtin_amdgcn_sched_barrier(0);
        }
        COMPUTE(1);
        __syncthreads();

        // epilogue: max_j within-lane over acc (+ hi-swap), sum_i butterfly over 32 col-lanes
        // C layout 32x32: row=(q&3)+8*(q>>2)+4*hi, col=lane&31
        #pragma unroll
        for (int jb = 0; jb < 2; ++jb) {
            float v0 = acc[2 * jb][0][0];
            float v1 = acc[2 * jb][1][0];
            #pragma unroll
            for (int m = 2 * jb; m <= 2 * jb + 1; ++m)
                #pragma unroll
                for (int q = 0; q < 16; ++q) {
                    if (m == 2 * jb && q == 0) continue;
                    v0 = fmaxf(v0, acc[m][0][q]);
                    v1 = fmaxf(v1, acc[m][1][q]);
                }
            v0 = fmaxf(v0, __shfl_xor(v0, 32)); // other 16 rows live in hi^1 lanes (same cols)
            v1 = fmaxf(v1, __shfl_xor(v1, 32));
            float s = v0 + v1;                  // two i-cols per lane
            #pragma unroll
            for (int d = 1; d <= 16; d <<= 1) s += __shfl_xor(s, d);
            if (lane == 0) {
                int a = pt * 4 + wn;
                int b = st * 4 + 2 * wm + jb;
                out[a * 256 + b] = s;
            }
        }
    }
#undef STAGE_SAT
#undef COMPUTE
}

extern "C" void kernel_launch(void* const* d_in, const int* in_sizes, int n_in,
                              void* d_out, int out_size, void* d_ws, size_t ws_size,
                              hipStream_t stream) {
    const float* sat  = (const float*)d_in[0];   // [16384,128]
    const float* pano = (const float*)d_in[1];   // [ 4096,128]
    float* out = (float*)d_out;                  // [64,256]

    unsigned short* panoN = (unsigned short*)d_ws;        // 4096*128 bf16
    unsigned short* satN  = panoN + (size_t)4096 * 128;   // 16384*128 bf16

    normalize_all<<<2560, 256, 0, stream>>>(sat, pano, satN, panoN);
    maxsim_kernel<<<256, 512, 0, stream>>>(satN, panoN, out);
}